// Round 4
// baseline (1556.249 us; speedup 1.0000x reference)
//
#include <hip/hip_runtime.h>
#include <math.h>

#define BB 4
#define N0 4096
#define NEWP 1152
#define GD 256
#define HD 128
#define KSEL 64
#define NSTEPS 10
#define NMAX (N0 + NSTEPS*NEWP)   /* 15616 */
#define NNEW (NSTEPS*NEWP)        /* 11520 */
#define F2S (BB*N0)               /* 16384: stride of f2buf[k][b*N0+i] */

/* ---- workspace layout (float offsets) ---- */
#define OFF_CANVAS 0
#define OFF_MINAB  (OFF_CANVAS + BB*NMAX*3)   /* reused region (uint), 2*BB*N0 */
#define OFF_MINCD  (OFF_MINAB + BB*NMAX)      /* reused region (uint), BB*(NNEW+N0) */
#define OFF_GMAX   (OFF_MINCD + BB*NMAX)
#define OFF_H      (OFF_GMAX + BB*GD)
#define OFF_C      (OFF_H + BB*HD)
#define OFF_ACC    (OFF_C + BB*HD)
#define OFF_CENTER (OFF_ACC + 16)             /* center[b*3] ; pf at +16+b*3 */
#define OFF_W2T    (OFF_CENTER + 32)
#define OFF_PART   (OFF_W2T + 128*64)         /* BB*64*8 softmax partials */
#define OFF_F2     (OFF_PART + BB*64*8)
#define WS_FLOATS  (OFF_F2 + 128*F2S)

__device__ __forceinline__ unsigned enc_f(float f){
  unsigned u = __float_as_uint(f);
  return (u & 0x80000000u) ? ~u : (u | 0x80000000u);
}
__device__ __forceinline__ float dec_f(unsigned e){
  unsigned u = (e & 0x80000000u) ? (e & 0x7fffffffu) : ~e;
  return __uint_as_float(u);
}
__device__ __forceinline__ float sigm(float x){ return 1.f/(1.f+expf(-x)); }

__device__ __forceinline__ float block_sum(float v, volatile float* red){
#pragma unroll
  for (int s=32;s>0;s>>=1) v += __shfl_down(v, s, 64);
  int lane = threadIdx.x & 63, w = threadIdx.x >> 6, nw = blockDim.x >> 6;
  __syncthreads();
  if (lane==0) red[w] = v;
  __syncthreads();
  if (w==0){
    float x = (lane < nw) ? red[lane] : 0.f;
#pragma unroll
    for (int s=8;s>0;s>>=1) x += __shfl_down(x, s, 64);
    if (lane==0) red[0] = x;
  }
  __syncthreads();
  float r = red[0];
  __syncthreads();
  return r;
}
__device__ __forceinline__ float block_max(float v, volatile float* red){
#pragma unroll
  for (int s=32;s>0;s>>=1) v = fmaxf(v, __shfl_down(v, s, 64));
  int lane = threadIdx.x & 63, w = threadIdx.x >> 6, nw = blockDim.x >> 6;
  __syncthreads();
  if (lane==0) red[w] = v;
  __syncthreads();
  if (w==0){
    float x = (lane < nw) ? red[lane] : -3.4e38f;
#pragma unroll
    for (int s=8;s>0;s>>=1) x = fmaxf(x, __shfl_down(x, s, 64));
    if (lane==0) red[0] = x;
  }
  __syncthreads();
  float r = red[0];
  __syncthreads();
  return r;
}

/* transpose enc_w2 (64x128)->w2t[j*64+k] */
__global__ __launch_bounds__(256) void prep_kernel(
    const float* __restrict__ w2, float* __restrict__ w2t)
{
  int i = blockIdx.x*256 + threadIdx.x;
  if (i < 128*64){ int j = i>>6, k = i&63; w2t[i] = w2[k*128 + j]; }
}

__global__ __launch_bounds__(256) void init_kernel(
    const float* __restrict__ points, float* __restrict__ canvas,
    float* __restrict__ h, float* __restrict__ c,
    unsigned* __restrict__ gmax)
{
  int i = blockIdx.x*256 + threadIdx.x;
  if (i < BB*N0*3){
    int b = i / (N0*3);
    int r = i - b*(N0*3);
    canvas[(size_t)b*NMAX*3 + r] = points[i];
  }
  if (i < BB*HD){ h[i] = 0.f; c[i] = 0.f; }
  if (i < BB*GD) gmax[i] = 0u;
}

/* encoder layers 1+2; jc = quarter (32) of the 128 outputs */
__global__ __launch_bounds__(256) void enc12_kernel(
    const float* __restrict__ canvas, const float* __restrict__ w1,
    const float* __restrict__ b1, const float* __restrict__ w2t,
    const float* __restrict__ b2, float* __restrict__ f2buf,
    int off, int M)
{
  int b = blockIdx.y;
  int jc = blockIdx.z;
  int i = blockIdx.x*256 + threadIdx.x;
  int ii = (i < M) ? i : 0;
  const float* p = canvas + (size_t)(b*NMAX + off + ii)*3;
  float p0 = p[0], p1 = p[1], p2 = p[2];
  float f1[64];
#pragma unroll
  for (int j=0;j<64;j++)
    f1[j] = fmaxf(0.f, b1[j] + p0*w1[j] + p1*w1[64+j] + p2*w1[128+j]);
  int base = b*N0 + ii;
#pragma unroll
  for (int j=0;j<32;j++){
    int jo = jc*32 + j;
    float a = b2[jo];
    const float* wr = w2t + jo*64;
#pragma unroll
    for (int k=0;k<64;k++) a += f1[k]*wr[k];
    if (i < M) f2buf[(size_t)jo*F2S + base] = fmaxf(0.f, a);
  }
}

/* encoder layer 3 + running-max pool. dc = 32-dim chunk (8 chunks). */
__global__ __launch_bounds__(256) void enc3_kernel(
    const float* __restrict__ f2buf, const float* __restrict__ w3,
    const float* __restrict__ b3, unsigned* __restrict__ gmax, int M)
{
  int b = blockIdx.y;
  int dc = blockIdx.z;
  int i = blockIdx.x*256 + threadIdx.x;
  bool act = i < M;
  int ii = act ? i : 0;
  const float* fp = f2buf + b*N0 + ii;
  float a[32];
#pragma unroll
  for (int d0=0; d0<32; d0++) a[d0] = b3[dc*32 + d0];
  for (int k=0;k<128;k++){
    float fk = fp[(size_t)k*F2S];          /* coalesced */
    const float* wr = w3 + k*256 + dc*32;  /* wave-uniform -> scalar loads */
#pragma unroll
    for (int d0=0; d0<32; d0++) a[d0] += fk * wr[d0];
  }
#pragma unroll
  for (int d0=0; d0<32; d0++){
    float v = act ? a[d0] : -3.4e38f;
#pragma unroll
    for (int s2=32;s2>0;s2>>=1) v = fmaxf(v, __shfl_down(v, s2, 64));
    if ((threadIdx.x & 63) == 0) atomicMax(&gmax[b*GD + dc*32 + d0], enc_f(v));
  }
}

/* attention scores + per-block online-softmax partials (m, se, wx, wy, wz). */
__global__ __launch_bounds__(256) void scores_kernel(
    const float* __restrict__ canvas, const float* __restrict__ aw1,
    const float* __restrict__ ab1, const float* __restrict__ aw2,
    const float* __restrict__ ab2, const unsigned* __restrict__ gmax,
    const float* __restrict__ h, float* __restrict__ part, int N)
{
  __shared__ float sBatt[128];
  __shared__ float red[8];
  int b = blockIdx.y;
  int tid = threadIdx.x;
  if (tid < 128){
    float a = ab1[tid];
    for (int k=0;k<GD;k++) a += dec_f(gmax[b*GD+k]) * aw1[(3+k)*128 + tid];
    for (int k=0;k<HD;k++) a += h[b*HD+k] * aw1[(3+GD+k)*128 + tid];
    sBatt[tid] = a;
  }
  __syncthreads();
  int i = blockIdx.x*256 + tid;
  bool act = i < N;
  float p0=0.f, p1=0.f, p2=0.f, s=-3.4e38f;
  if (act){
    const float* p = canvas + (size_t)(b*NMAX + i)*3;
    p0 = p[0]; p1 = p[1]; p2 = p[2];
    s = ab2[0];
    for (int j=0;j<128;j++){
      float t = sBatt[j] + p0*aw1[j] + p1*aw1[128+j] + p2*aw1[256+j];
      s += fmaxf(t, 0.f) * aw2[j];
    }
  }
  float mb = block_max(s, red);
  float e = act ? expf(s - mb) : 0.f;
  float se = block_sum(e, red);
  float wx = block_sum(e*p0, red);
  float wy = block_sum(e*p1, red);
  float wz = block_sum(e*p2, red);
  if (tid == 0){
    float* pp = part + (size_t)(b*64 + blockIdx.x)*8;
    pp[0]=mb; pp[1]=se; pp[2]=wx; pp[3]=wy; pp[4]=wz;
  }
}

/* per-batch: combine softmax partials -> center; binary-search top-64
   threshold (no LDS atomics, no scans); patch mean; write center+pf. */
__global__ __launch_bounds__(1024) void stepA_kernel(
    const float* __restrict__ canvas, const float* __restrict__ part,
    float* __restrict__ centerpf, int N, int nblk)
{
  __shared__ float red[32];
  __shared__ float sC[3];
  __shared__ int cntbuf[2][16];
  __shared__ int tieCnt;
  __shared__ int tieIdx[256];

  int b = blockIdx.x;
  int tid = threadIdx.x;
  int lane = tid & 63, wid = tid >> 6;
  const float* cv = canvas + (size_t)b*NMAX*3;

  /* --- phase 0: combine per-block softmax partials --- */
  float pm=-3.4e38f, pse=0.f, pwx=0.f, pwy=0.f, pwz=0.f;
  if (tid < nblk){
    const float* pp = part + (size_t)(b*64 + tid)*8;
    pm=pp[0]; pse=pp[1]; pwx=pp[2]; pwy=pp[3]; pwz=pp[4];
  }
  float M = block_max(pm, red);
  float w = (tid < nblk) ? expf(pm - M) : 0.f;
  float se = block_sum(pse*w, red);
  float wx = block_sum(pwx*w, red);
  float wy = block_sum(pwy*w, red);
  float wz = block_sum(pwz*w, red);
  if (tid==0){ sC[0]=wx/se; sC[1]=wy/se; sC[2]=wz/se; }
  __syncthreads();
  float cx=sC[0], cy=sC[1], cz=sC[2];
  if (tid<3) centerpf[b*3+tid] = sC[tid];

  /* --- phase 1: d2 bits into registers --- */
  int qmax = (N + 1023) >> 10;
  unsigned ur[16];
#pragma unroll
  for (int q=0;q<16;q++){
    ur[q] = 0xFFFFFFFFu;
    int i = tid + q*1024;
    if (q < qmax && i < N){
      const float* p = cv + (size_t)i*3;
      float dx=p[0]-cx, dy=p[1]-cy, dz=p[2]-cz;
      ur[q] = __float_as_uint(dx*dx + dy*dy + dz*dz);
    }
  }

  /* --- binary search for T = 64th smallest u (d2 >= 0 -> bit31 clear) --- */
  unsigned T = 0u;
  int cntBelow = 0;
  int par = 0;
  for (int bit=30; bit>=0; bit--){
    unsigned cand = T | (1u<<bit);
    int tc = 0;
#pragma unroll
    for (int q=0;q<16;q++) tc += (ur[q] < cand) ? 1 : 0;
#pragma unroll
    for (int s=32;s>0;s>>=1) tc += __shfl_down(tc, s, 64);
    if (lane==0) cntbuf[par][wid] = tc;
    __syncthreads();
    int tot = 0;
#pragma unroll
    for (int i2=0;i2<16;i2++) tot += cntbuf[par][i2];
    if (tot < KSEL){ T = cand; cntBelow = tot; }
    par ^= 1;
  }
  int kneed = KSEL - cntBelow;

  /* --- sum coords below T; collect ties --- */
  if (tid==0) tieCnt = 0;
  __syncthreads();
  float sx=0.f, sy=0.f, sz=0.f;
#pragma unroll
  for (int q=0;q<16;q++){
    unsigned u = ur[q];
    if (u < T){
      const float* p = cv + (size_t)(tid + q*1024)*3;
      sx += p[0]; sy += p[1]; sz += p[2];
    } else if (u == T){
      int pos = atomicAdd(&tieCnt, 1);
      if (pos < 256) tieIdx[pos] = tid + q*1024;
    }
  }
  __syncthreads();
  sx = block_sum(sx, red);
  sy = block_sum(sy, red);
  sz = block_sum(sz, red);
  if (tid==0){
    int mm = tieCnt < 256 ? tieCnt : 256;
    for (int t=0;t<kneed;t++){
      int best=-1, bi=0x7fffffff;
      for (int q=0;q<mm;q++){ int v = tieIdx[q]; if (v < bi){ bi=v; best=q; } }
      if (best >= 0){
        tieIdx[best] = 0x7fffffff;
        const float* p = cv + (size_t)bi*3;
        sx += p[0]; sy += p[1]; sz += p[2];
      }
    }
    centerpf[16 + b*3 + 0] = sx/KSEL - cx;
    centerpf[16 + b*3 + 1] = sy/KSEL - cy;
    centerpf[16 + b*3 + 2] = sz/KSEL - cz;
  }
}

/* LSTM: 8 blocks, each owns 16 h-dims x 4 gates x 4 batches.
   Weight stream (798KB) parallel across 8 CUs, each slice read once. */
__global__ __launch_bounds__(256) void lstm_kernel(
    const unsigned* __restrict__ gmax, const float* __restrict__ centerpf,
    float* __restrict__ h, float* __restrict__ c,
    const float* __restrict__ wih, const float* __restrict__ whh,
    const float* __restrict__ bih, const float* __restrict__ bhh)
{
  __shared__ float sIn[BB][GD+6];
  __shared__ float sH[BB][HD];
  __shared__ float sG[BB][64];
  int blk = blockIdx.x;            /* 0..7 */
  int tid = threadIdx.x;
  int b = tid>>6, l = tid&63, g = l>>4, t = l&15;
  for (int i=tid; i<BB*(GD+6); i+=256){
    int bb = i/(GD+6), k = i%(GD+6);
    float v;
    if (k < GD) v = dec_f(gmax[bb*GD + k]);
    else if (k < GD+3) v = centerpf[bb*3 + (k-GD)];
    else v = centerpf[16 + bb*3 + (k-GD-3)];
    sIn[bb][k] = v;
  }
  for (int i=tid; i<BB*HD; i+=256) sH[i>>7][i&127] = h[i];
  __syncthreads();
  int o = g*128 + blk*16 + t;
  float a = bih[o] + bhh[o];
  for (int k=0;k<GD+6;k++) a += sIn[b][k]*wih[k*512 + o];
  for (int k=0;k<HD;k++)   a += sH[b][k]*whh[k*512 + o];
  sG[b][g*16+t] = a;
  __syncthreads();
  if (g==0){
    int j = blk*16 + t;
    float gi=sG[b][t], gf=sG[b][16+t], gg=sG[b][32+t], go=sG[b][48+t];
    float cn = sigm(gf)*c[b*HD+j] + sigm(gi)*tanhf(gg);
    float hn = sigm(go)*tanhf(cn);
    c[b*HD+j]=cn; h[b*HD+j]=hn;
  }
}

/* refinement decoder */
__global__ __launch_bounds__(256) void refine_kernel(
    float* __restrict__ canvas, const float* __restrict__ h,
    const float* __restrict__ centerpf,
    const float* __restrict__ rw1, const float* __restrict__ rb1,
    const float* __restrict__ rw2, const float* __restrict__ rb2, int N)
{
  __shared__ float sRf[HD];
  int b = blockIdx.y;
  int tid = threadIdx.x;
  if (tid < HD){
    float a = rb1[tid];
    for (int k=0;k<HD;k++) a += h[b*HD+k]*rw1[k*HD + tid];
    sRf[tid] = fmaxf(a, 0.f);
  }
  __syncthreads();
  int o = blockIdx.x*256 + tid;
  if (o < NEWP*3){
    float a = rb2[o];
    for (int k=0;k<HD;k++) a += sRf[k]*rw2[k*(NEWP*3) + o];
    canvas[((size_t)b*NMAX + N)*3 + o] = a*0.02f + centerpf[b*3 + (o%3)];
  }
}

/* ---- chamfer: dot form, SoA LDS y-tiles, flat 256-block grid ---- */
#define CYT 1024

__global__ __launch_bounds__(256) void chamfer_init_kernel(
    unsigned* __restrict__ minAB, unsigned* __restrict__ minCD)
{
  int i = blockIdx.x*256 + threadIdx.x;
  if (i < 2*BB*N0) minAB[i] = 0xFFFFFFFFu;
  if (i < BB*NNEW + BB*N0) minCD[i] = 0xFFFFFFFFu;
}

__global__ __launch_bounds__(512) void chamfer_kernel(
    const float* __restrict__ canvas, const float* __restrict__ gt,
    unsigned* __restrict__ minAB, unsigned* __restrict__ minCD)
{
  __shared__ float sy0[CYT], sy1[CYT], sy2[CYT], sny[CYT];
  int id = blockIdx.x;
  int dir, rem;
  if (id < 32){ dir=0; rem=id; }
  else if (id < 64){ dir=1; rem=id-32; }
  else if (id < 160){ dir=2; rem=id-64; }
  else { dir=3; rem=id-160; }
  int b, xb, yb;
  if (dir < 2){ b = rem>>3; int l = rem&7; xb = l>>2; yb = l&3; }
  else if (dir == 2){ b = rem/24; int l = rem%24; xb = l>>2; yb = l&3; }
  else { b = rem/24; int l = rem%24; xb = l/12; yb = l%12; }

  int Nx, Ny; const float* X; const float* Y; unsigned* mp;
  if (dir==0){      Nx=N0;   Ny=N0;   X=canvas+(size_t)b*NMAX*3;       Y=gt+(size_t)b*N0*3;            mp=minAB + b*N0; }
  else if (dir==1){ Nx=N0;   Ny=N0;   X=gt+(size_t)b*N0*3;             Y=canvas+(size_t)b*NMAX*3;      mp=minAB + BB*N0 + b*N0; }
  else if (dir==2){ Nx=NNEW; Ny=N0;   X=canvas+((size_t)b*NMAX+N0)*3;  Y=gt+(size_t)b*N0*3;            mp=minCD + b*NNEW; }
  else {            Nx=N0;   Ny=NNEW; X=gt+(size_t)b*N0*3;             Y=canvas+((size_t)b*NMAX+N0)*3; mp=minCD + BB*NNEW + b*N0; }

  int xbase = xb*2048;
  int ybase = yb*CYT;
  int tn = min(CYT, Ny - ybase);
  int tid = threadIdx.x;
  for (int t=tid; t<tn; t+=512){
    const float* yp = Y + (size_t)(ybase+t)*3;
    float y0=yp[0], y1=yp[1], y2=yp[2];
    sy0[t]=y0; sy1[t]=y1; sy2[t]=y2; sny[t]=y0*y0+y1*y1+y2*y2;
  }
  __syncthreads();

  float X0[4],X1[4],X2[4],NXr[4],MN[4]; int XI[4]; bool VA[4];
#pragma unroll
  for (int q=0;q<4;q++){
    int x = xbase + q*512 + tid;
    VA[q] = x < Nx;
    int xc = VA[q] ? x : 0;
    const float* xp = X + (size_t)xc*3;
    X0[q]=xp[0]; X1[q]=xp[1]; X2[q]=xp[2];
    NXr[q] = X0[q]*X0[q] + X1[q]*X1[q] + X2[q]*X2[q];
    MN[q] = 3.4e38f; XI[q] = xc;
  }
  const float4* v0 = (const float4*)sy0;
  const float4* v1 = (const float4*)sy1;
  const float4* v2 = (const float4*)sy2;
  const float4* vn = (const float4*)sny;
  int j4n = tn >> 2;
  for (int j=0;j<j4n;j++){
    float4 a0 = v0[j], a1 = v1[j], a2 = v2[j], an = vn[j];
#pragma unroll
    for (int e=0;e<4;e++){
      float y0 = ((const float*)&a0)[e];
      float y1 = ((const float*)&a1)[e];
      float y2 = ((const float*)&a2)[e];
      float ny = ((const float*)&an)[e];
#pragma unroll
      for (int q=0;q<4;q++){
        float dot = fmaf(X0[q], y0, fmaf(X1[q], y1, X2[q]*y2));
        float d   = fmaf(-2.f, dot, ny);
        MN[q] = fminf(MN[q], d);
      }
    }
  }
  for (int j=j4n*4; j<tn; j++){
    float y0=sy0[j], y1=sy1[j], y2=sy2[j], ny=sny[j];
#pragma unroll
    for (int q=0;q<4;q++){
      float dot = fmaf(X0[q], y0, fmaf(X1[q], y1, X2[q]*y2));
      MN[q] = fminf(MN[q], fmaf(-2.f, dot, ny));
    }
  }
#pragma unroll
  for (int q=0;q<4;q++)
    if (VA[q]) atomicMin(&mp[XI[q]], enc_f(MN[q] + NXr[q]));
}

__global__ __launch_bounds__(256) void chamfer_reduce_kernel(
    const unsigned* __restrict__ minAB, const unsigned* __restrict__ minCD,
    float* __restrict__ acc)
{
  __shared__ float red[8];
  int s = blockIdx.x, dir = s>>2, b = s&3;
  const unsigned* mp; int len;
  if (dir==0){      mp=minAB + b*N0;            len=N0; }
  else if (dir==1){ mp=minAB + BB*N0 + b*N0;    len=N0; }
  else if (dir==2){ mp=minCD + b*NNEW;          len=NNEW; }
  else {            mp=minCD + BB*NNEW + b*N0;  len=N0; }
  float v = 0.f;
  for (int i=threadIdx.x;i<len;i+=256) v += dec_f(mp[i]);
  v = block_sum(v, red);
  if (threadIdx.x==0) acc[s] = v;
}

__global__ void finish_kernel(const float* __restrict__ acc, float* __restrict__ out)
{
  if (threadIdx.x == 0 && blockIdx.x == 0){
    float cd1 = 0.f, cd2 = 0.f;
    for (int b=0;b<BB;b++) cd1 += acc[b]/(float)N0 + acc[4+b]/(float)N0;
    for (int b=0;b<BB;b++) cd2 += acc[8+b]/(float)NNEW + acc[12+b]/(float)N0;
    out[0] = 0.1f*(cd1/BB) + 1.0f*(cd2/BB);
  }
}

extern "C" void kernel_launch(void* const* d_in, const int* in_sizes, int n_in,
                              void* d_out, int out_size, void* d_ws, size_t ws_size,
                              hipStream_t stream) {
  (void)in_sizes; (void)n_in; (void)out_size; (void)ws_size;
  const float* points   = (const float*)d_in[0];
  const float* gt       = (const float*)d_in[1];
  const float* enc_w1   = (const float*)d_in[2];
  const float* enc_b1   = (const float*)d_in[3];
  const float* enc_w2   = (const float*)d_in[4];
  const float* enc_b2   = (const float*)d_in[5];
  const float* enc_w3   = (const float*)d_in[6];
  const float* enc_b3   = (const float*)d_in[7];
  const float* att_w1   = (const float*)d_in[8];
  const float* att_b1   = (const float*)d_in[9];
  const float* att_w2   = (const float*)d_in[10];
  const float* att_b2   = (const float*)d_in[11];
  const float* lstm_wih = (const float*)d_in[12];
  const float* lstm_whh = (const float*)d_in[13];
  const float* lstm_bih = (const float*)d_in[14];
  const float* lstm_bhh = (const float*)d_in[15];
  const float* ref_w1   = (const float*)d_in[16];
  const float* ref_b1   = (const float*)d_in[17];
  const float* ref_w2   = (const float*)d_in[18];
  const float* ref_b2   = (const float*)d_in[19];
  float* out = (float*)d_out;

  float* ws      = (float*)d_ws;
  float* canvas  = ws + OFF_CANVAS;
  unsigned* minAB = (unsigned*)(ws + OFF_MINAB);
  unsigned* minCD = (unsigned*)(ws + OFF_MINCD);
  unsigned* gmaxp = (unsigned*)(ws + OFF_GMAX);
  float* hb      = ws + OFF_H;
  float* cb      = ws + OFF_C;
  float* acc     = ws + OFF_ACC;
  float* centerb = ws + OFF_CENTER;
  float* w2t     = ws + OFF_W2T;
  float* partb   = ws + OFF_PART;
  float* f2buf   = ws + OFF_F2;

  prep_kernel<<<dim3(32), 256, 0, stream>>>(enc_w2, w2t);
  init_kernel<<<dim3(192), 256, 0, stream>>>(points, canvas, hb, cb, gmaxp);

  for (int t=0; t<NSTEPS; t++){
    int off = (t==0) ? 0 : (N0 + (t-1)*NEWP);
    int M   = (t==0) ? N0 : NEWP;
    int N   = N0 + t*NEWP;
    int nbM = (M + 255)/256;
    int nbN = (N + 255)/256;
    enc12_kernel<<<dim3(nbM, BB, 4), 256, 0, stream>>>(canvas, enc_w1, enc_b1, w2t, enc_b2, f2buf, off, M);
    enc3_kernel<<<dim3(nbM, BB, 8), 256, 0, stream>>>(f2buf, enc_w3, enc_b3, gmaxp, M);
    scores_kernel<<<dim3(nbN, BB), 256, 0, stream>>>(canvas, att_w1, att_b1, att_w2, att_b2, gmaxp, hb, partb, N);
    stepA_kernel<<<dim3(BB), 1024, 0, stream>>>(canvas, partb, centerb, N, nbN);
    lstm_kernel<<<dim3(8), 256, 0, stream>>>(gmaxp, centerb, hb, cb, lstm_wih, lstm_whh, lstm_bih, lstm_bhh);
    refine_kernel<<<dim3(14, BB), 256, 0, stream>>>(canvas, hb, centerb, ref_w1, ref_b1, ref_w2, ref_b2, N);
  }

  chamfer_init_kernel<<<dim3((BB*NMAX + 255)/256), 256, 0, stream>>>(minAB, minCD);
  chamfer_kernel<<<dim3(256), 512, 0, stream>>>(canvas, gt, minAB, minCD);
  chamfer_reduce_kernel<<<dim3(16), 256, 0, stream>>>(minAB, minCD, acc);
  finish_kernel<<<1, 64, 0, stream>>>(acc, out);
}

// Round 5
// 1330.987 us; speedup vs baseline: 1.1692x; 1.1692x over previous
//
#include <hip/hip_runtime.h>
#include <math.h>

#define BB 4
#define N0 4096
#define NEWP 1152
#define GD 256
#define HD 128
#define KSEL 64
#define NSTEPS 10
#define NMAX (N0 + NSTEPS*NEWP)   /* 15616 */
#define NNEW (NSTEPS*NEWP)        /* 11520 */
#define F2S (BB*N0)               /* 16384: stride of f2buf[k][b*N0+i] */

/* ---- workspace layout (float offsets) ---- */
#define OFF_CANVAS 0
#define OFF_MINAB  (OFF_CANVAS + BB*NMAX*3)
#define OFF_MINCD  (OFF_MINAB + BB*NMAX)
#define OFF_GMAX   (OFF_MINCD + BB*NMAX)
#define OFF_H      (OFF_GMAX + BB*GD)          /* 2 buffers of BB*HD */
#define OFF_C      (OFF_H + 2*BB*HD)           /* 2 buffers of BB*HD */
#define OFF_ACC    (OFF_C + 2*BB*HD)
#define OFF_CENTER (OFF_ACC + 16)              /* center[b*3]; pf at +16+b*3 */
#define OFF_W2T    (OFF_CENTER + 32)
#define OFF_PART   (OFF_W2T + 128*64)          /* BB*64*8 softmax partials */
#define OFF_GPART  (OFF_PART + BB*64*8)        /* 32*BB*512 lstm partials */
#define OFF_F2     (OFF_GPART + 32*BB*512)
#define WS_FLOATS  (OFF_F2 + 128*F2S)

__device__ __forceinline__ unsigned enc_f(float f){
  unsigned u = __float_as_uint(f);
  return (u & 0x80000000u) ? ~u : (u | 0x80000000u);
}
__device__ __forceinline__ float dec_f(unsigned e){
  unsigned u = (e & 0x80000000u) ? (e & 0x7fffffffu) : ~e;
  return __uint_as_float(u);
}
__device__ __forceinline__ float sigm(float x){ return 1.f/(1.f+expf(-x)); }

__device__ __forceinline__ float block_sum(float v, volatile float* red){
#pragma unroll
  for (int s=32;s>0;s>>=1) v += __shfl_down(v, s, 64);
  int lane = threadIdx.x & 63, w = threadIdx.x >> 6, nw = blockDim.x >> 6;
  __syncthreads();
  if (lane==0) red[w] = v;
  __syncthreads();
  if (w==0){
    float x = (lane < nw) ? red[lane] : 0.f;
#pragma unroll
    for (int s=8;s>0;s>>=1) x += __shfl_down(x, s, 64);
    if (lane==0) red[0] = x;
  }
  __syncthreads();
  float r = red[0];
  __syncthreads();
  return r;
}
__device__ __forceinline__ float block_max(float v, volatile float* red){
#pragma unroll
  for (int s=32;s>0;s>>=1) v = fmaxf(v, __shfl_down(v, s, 64));
  int lane = threadIdx.x & 63, w = threadIdx.x >> 6, nw = blockDim.x >> 6;
  __syncthreads();
  if (lane==0) red[w] = v;
  __syncthreads();
  if (w==0){
    float x = (lane < nw) ? red[lane] : -3.4e38f;
#pragma unroll
    for (int s=8;s>0;s>>=1) x = fmaxf(x, __shfl_down(x, s, 64));
    if (lane==0) red[0] = x;
  }
  __syncthreads();
  float r = red[0];
  __syncthreads();
  return r;
}

/* transpose enc_w2 (64x128)->w2t[j*64+k] */
__global__ __launch_bounds__(256) void prep_kernel(
    const float* __restrict__ w2, float* __restrict__ w2t)
{
  int i = blockIdx.x*256 + threadIdx.x;
  if (i < 128*64){ int j = i>>6, k = i&63; w2t[i] = w2[k*128 + j]; }
}

__global__ __launch_bounds__(256) void init_kernel(
    const float* __restrict__ points, float* __restrict__ canvas,
    float* __restrict__ h, float* __restrict__ c,
    unsigned* __restrict__ gmax)
{
  int i = blockIdx.x*256 + threadIdx.x;
  if (i < BB*N0*3){
    int b = i / (N0*3);
    int r = i - b*(N0*3);
    canvas[(size_t)b*NMAX*3 + r] = points[i];
  }
  if (i < 2*BB*HD){ h[i] = 0.f; c[i] = 0.f; }
  if (i < BB*GD) gmax[i] = 0u;
}

/* encoder layers 1+2; jc = quarter (32) of the 128 outputs */
__global__ __launch_bounds__(256) void enc12_kernel(
    const float* __restrict__ canvas, const float* __restrict__ w1,
    const float* __restrict__ b1, const float* __restrict__ w2t,
    const float* __restrict__ b2, float* __restrict__ f2buf,
    int off, int M)
{
  int b = blockIdx.y;
  int jc = blockIdx.z;
  int i = blockIdx.x*256 + threadIdx.x;
  int ii = (i < M) ? i : 0;
  const float* p = canvas + (size_t)(b*NMAX + off + ii)*3;
  float p0 = p[0], p1 = p[1], p2 = p[2];
  float f1[64];
#pragma unroll
  for (int j=0;j<64;j++)
    f1[j] = fmaxf(0.f, b1[j] + p0*w1[j] + p1*w1[64+j] + p2*w1[128+j]);
  int base = b*N0 + ii;
#pragma unroll
  for (int j=0;j<32;j++){
    int jo = jc*32 + j;
    float a = b2[jo];
    const float* wr = w2t + jo*64;
#pragma unroll
    for (int k=0;k<64;k++) a += f1[k]*wr[k];
    if (i < M) f2buf[(size_t)jo*F2S + base] = fmaxf(0.f, a);
  }
}

/* encoder layer 3 + running-max pool. dc = 32-dim chunk (8 chunks). */
__global__ __launch_bounds__(256) void enc3_kernel(
    const float* __restrict__ f2buf, const float* __restrict__ w3,
    const float* __restrict__ b3, unsigned* __restrict__ gmax, int M)
{
  int b = blockIdx.y;
  int dc = blockIdx.z;
  int i = blockIdx.x*256 + threadIdx.x;
  bool act = i < M;
  int ii = act ? i : 0;
  const float* fp = f2buf + b*N0 + ii;
  float a[32];
#pragma unroll
  for (int d0=0; d0<32; d0++) a[d0] = b3[dc*32 + d0];
  for (int k=0;k<128;k++){
    float fk = fp[(size_t)k*F2S];
    const float* wr = w3 + k*256 + dc*32;
#pragma unroll
    for (int d0=0; d0<32; d0++) a[d0] += fk * wr[d0];
  }
#pragma unroll
  for (int d0=0; d0<32; d0++){
    float v = act ? a[d0] : -3.4e38f;
#pragma unroll
    for (int s2=32;s2>0;s2>>=1) v = fmaxf(v, __shfl_down(v, s2, 64));
    if ((threadIdx.x & 63) == 0) atomicMax(&gmax[b*GD + dc*32 + d0], enc_f(v));
  }
}

/* LSTM split-K: 32 blocks, chunk c owns 12 rows of [wih(0:256); whh(0:128)].
   Coalesced row streaming, 4-batch weight reuse, deterministic partials. */
__global__ __launch_bounds__(256) void lstm_main_kernel(
    const unsigned* __restrict__ gmax, const float* __restrict__ h_in,
    const float* __restrict__ wih, const float* __restrict__ whh,
    float* __restrict__ gpart)
{
  __shared__ float sV[BB][12];
  int cchunk = blockIdx.x;
  int tid = threadIdx.x;
  int r0 = cchunk*12;
  if (tid < BB*12){
    int b = tid/12, j = tid%12;
    int r = r0 + j;
    sV[b][j] = (r < 256) ? dec_f(gmax[b*GD + r]) : h_in[b*HD + (r-256)];
  }
  __syncthreads();
  int o0 = tid, o1 = tid + 256;
  float a00=0.f,a01=0.f,a10=0.f,a11=0.f,a20=0.f,a21=0.f,a30=0.f,a31=0.f;
#pragma unroll
  for (int j=0;j<12;j++){
    int r = r0 + j;
    const float* wr = (r < 256) ? (wih + (size_t)r*512) : (whh + (size_t)(r-256)*512);
    float w0 = wr[o0], w1 = wr[o1];
    float v0=sV[0][j], v1=sV[1][j], v2=sV[2][j], v3=sV[3][j];
    a00 += v0*w0; a01 += v0*w1;
    a10 += v1*w0; a11 += v1*w1;
    a20 += v2*w0; a21 += v2*w1;
    a30 += v3*w0; a31 += v3*w1;
  }
  float* gp = gpart + (size_t)cchunk*(BB*512);
  gp[0*512+o0]=a00; gp[0*512+o1]=a01;
  gp[1*512+o0]=a10; gp[1*512+o1]=a11;
  gp[2*512+o0]=a20; gp[2*512+o1]=a21;
  gp[3*512+o0]=a30; gp[3*512+o1]=a31;
}

/* attention scores + per-block online-softmax partials */
__global__ __launch_bounds__(256) void scores_kernel(
    const float* __restrict__ canvas, const float* __restrict__ aw1,
    const float* __restrict__ ab1, const float* __restrict__ aw2,
    const float* __restrict__ ab2, const unsigned* __restrict__ gmax,
    const float* __restrict__ h, float* __restrict__ part, int N)
{
  __shared__ float sBatt[128];
  __shared__ float red[8];
  int b = blockIdx.y;
  int tid = threadIdx.x;
  if (tid < 128){
    float a = ab1[tid];
    for (int k=0;k<GD;k++) a += dec_f(gmax[b*GD+k]) * aw1[(3+k)*128 + tid];
    for (int k=0;k<HD;k++) a += h[b*HD+k] * aw1[(3+GD+k)*128 + tid];
    sBatt[tid] = a;
  }
  __syncthreads();
  int i = blockIdx.x*256 + tid;
  bool act = i < N;
  float p0=0.f, p1=0.f, p2=0.f, s=-3.4e38f;
  if (act){
    const float* p = canvas + (size_t)(b*NMAX + i)*3;
    p0 = p[0]; p1 = p[1]; p2 = p[2];
    s = ab2[0];
    for (int j=0;j<128;j++){
      float t = sBatt[j] + p0*aw1[j] + p1*aw1[128+j] + p2*aw1[256+j];
      s += fmaxf(t, 0.f) * aw2[j];
    }
  }
  float mb = block_max(s, red);
  float e = act ? expf(s - mb) : 0.f;
  float se = block_sum(e, red);
  float wx = block_sum(e*p0, red);
  float wy = block_sum(e*p1, red);
  float wz = block_sum(e*p2, red);
  if (tid == 0){
    float* pp = part + (size_t)(b*64 + blockIdx.x)*8;
    pp[0]=mb; pp[1]=se; pp[2]=wx; pp[3]=wy; pp[4]=wz;
  }
}

/* per-batch: combine softmax partials -> center; 2-bit-per-iter threshold
   search (16 barriers); patch mean; write center+pf. */
__global__ __launch_bounds__(1024) void stepA_kernel(
    const float* __restrict__ canvas, const float* __restrict__ part,
    float* __restrict__ centerpf, int N, int nblk)
{
  __shared__ float red[32];
  __shared__ float sC[3];
  __shared__ unsigned cbufA[2][16];
  __shared__ unsigned cbufB[2][16];
  __shared__ int tieCnt;
  __shared__ int tieIdx[256];

  int b = blockIdx.x;
  int tid = threadIdx.x;
  int lane = tid & 63, wid = tid >> 6;
  const float* cv = canvas + (size_t)b*NMAX*3;

  /* phase 0: combine per-block softmax partials */
  float pm=-3.4e38f, pse=0.f, pwx=0.f, pwy=0.f, pwz=0.f;
  if (tid < nblk){
    const float* pp = part + (size_t)(b*64 + tid)*8;
    pm=pp[0]; pse=pp[1]; pwx=pp[2]; pwy=pp[3]; pwz=pp[4];
  }
  float M = block_max(pm, red);
  float w = (tid < nblk) ? expf(pm - M) : 0.f;
  float se = block_sum(pse*w, red);
  float wx = block_sum(pwx*w, red);
  float wy = block_sum(pwy*w, red);
  float wz = block_sum(pwz*w, red);
  if (tid==0){ sC[0]=wx/se; sC[1]=wy/se; sC[2]=wz/se; }
  __syncthreads();
  float cx=sC[0], cy=sC[1], cz=sC[2];
  if (tid<3) centerpf[b*3+tid] = sC[tid];

  /* phase 1: d2 bits into registers */
  unsigned ur[16];
#pragma unroll
  for (int q=0;q<16;q++){
    ur[q] = 0xFFFFFFFFu;
    int i = tid + q*1024;
    if (i < N){
      const float* p = cv + (size_t)i*3;
      float dx=p[0]-cx, dy=p[1]-cy, dz=p[2]-cz;
      ur[q] = __float_as_uint(dx*dx + dy*dy + dz*dz);
    }
  }

  /* threshold binary search, 2 bits per iteration */
  unsigned T = 0u;
  int cntBelow = 0;
  int par = 0;
  {
    /* bit 30 alone */
    unsigned cand = 1u<<30;
    unsigned tc = 0;
#pragma unroll
    for (int q=0;q<16;q++) tc += (ur[q] < cand) ? 1u : 0u;
#pragma unroll
    for (int s=32;s>0;s>>=1) tc += __shfl_down(tc, s, 64);
    if (lane==0) cbufA[par][wid] = tc;
    __syncthreads();
    unsigned tot = 0;
#pragma unroll
    for (int i2=0;i2<16;i2++) tot += cbufA[par][i2];
    if ((int)tot < KSEL){ T = cand; cntBelow = (int)tot; }
    par ^= 1;
  }
  for (int bit=29; bit>=1; bit-=2){
    unsigned q1 = 1u<<(bit-1);
    unsigned c1 = T + q1, c2 = T + 2u*q1, c3 = T + 3u*q1;
    unsigned ta = 0, tb = 0;   /* ta: n1 | n2<<16 ; tb: n3 */
#pragma unroll
    for (int q=0;q<16;q++){
      unsigned u = ur[q];
      ta += (u < c1 ? 1u : 0u) | (u < c2 ? 0x10000u : 0u);
      tb += (u < c3 ? 1u : 0u);
    }
#pragma unroll
    for (int s=32;s>0;s>>=1){ ta += __shfl_down(ta, s, 64); tb += __shfl_down(tb, s, 64); }
    if (lane==0){ cbufA[par][wid] = ta; cbufB[par][wid] = tb; }
    __syncthreads();
    unsigned sa = 0, sb = 0;
#pragma unroll
    for (int i2=0;i2<16;i2++){ sa += cbufA[par][i2]; sb += cbufB[par][i2]; }
    int n1 = (int)(sa & 0xFFFFu), n2 = (int)(sa >> 16), n3 = (int)sb;
    if (n3 < KSEL){ T = c3; cntBelow = n3; }
    else if (n2 < KSEL){ T = c2; cntBelow = n2; }
    else if (n1 < KSEL){ T = c1; cntBelow = n1; }
    par ^= 1;
  }
  int kneed = KSEL - cntBelow;

  /* sum coords below T; collect ties */
  if (tid==0) tieCnt = 0;
  __syncthreads();
  float sx=0.f, sy=0.f, sz=0.f;
#pragma unroll
  for (int q=0;q<16;q++){
    unsigned u = ur[q];
    if (u < T){
      const float* p = cv + (size_t)(tid + q*1024)*3;
      sx += p[0]; sy += p[1]; sz += p[2];
    } else if (u == T){
      int pos = atomicAdd(&tieCnt, 1);
      if (pos < 256) tieIdx[pos] = tid + q*1024;
    }
  }
  __syncthreads();
  sx = block_sum(sx, red);
  sy = block_sum(sy, red);
  sz = block_sum(sz, red);
  if (tid==0){
    int mm = tieCnt < 256 ? tieCnt : 256;
    for (int t=0;t<kneed;t++){
      int best=-1, bi=0x7fffffff;
      for (int q=0;q<mm;q++){ int v = tieIdx[q]; if (v < bi){ bi=v; best=q; } }
      if (best >= 0){
        tieIdx[best] = 0x7fffffff;
        const float* p = cv + (size_t)bi*3;
        sx += p[0]; sy += p[1]; sz += p[2];
      }
    }
    centerpf[16 + b*3 + 0] = sx/KSEL - cx;
    centerpf[16 + b*3 + 1] = sy/KSEL - cy;
    centerpf[16 + b*3 + 2] = sz/KSEL - cz;
  }
}

/* refinement decoder with fused LSTM finish.
   Every block redundantly finishes the gates (sum 32 partials + bias +
   center/pf rows); block x==0 writes double-buffered h/c. */
__global__ __launch_bounds__(256) void refine_kernel(
    float* __restrict__ canvas, const float* __restrict__ gpart,
    const float* __restrict__ centerpf,
    const float* __restrict__ c_in, float* __restrict__ c_out,
    float* __restrict__ h_out,
    const float* __restrict__ wih,
    const float* __restrict__ bih, const float* __restrict__ bhh,
    const float* __restrict__ rw1, const float* __restrict__ rb1,
    const float* __restrict__ rw2, const float* __restrict__ rb2, int N)
{
  __shared__ float sG[512];
  __shared__ float sH[HD];
  __shared__ float sRf[HD];
  int b = blockIdx.y;
  int tid = threadIdx.x;
  float cx = centerpf[b*3+0], cy = centerpf[b*3+1], cz = centerpf[b*3+2];
  float fx = centerpf[16+b*3+0], fy = centerpf[16+b*3+1], fz = centerpf[16+b*3+2];
#pragma unroll
  for (int half=0; half<2; half++){
    int o = tid + half*256;
    float g = bih[o] + bhh[o];
    for (int cc=0; cc<32; cc++) g += gpart[(size_t)cc*(BB*512) + b*512 + o];
    g += cx*wih[(size_t)256*512+o] + cy*wih[(size_t)257*512+o] + cz*wih[(size_t)258*512+o];
    g += fx*wih[(size_t)259*512+o] + fy*wih[(size_t)260*512+o] + fz*wih[(size_t)261*512+o];
    sG[o] = g;
  }
  __syncthreads();
  if (tid < HD){
    float gi=sG[tid], gf=sG[128+tid], gg=sG[256+tid], go=sG[384+tid];
    float cn = sigm(gf)*c_in[b*HD+tid] + sigm(gi)*tanhf(gg);
    float hn = sigm(go)*tanhf(cn);
    sH[tid] = hn;
    if (blockIdx.x==0){ c_out[b*HD+tid]=cn; h_out[b*HD+tid]=hn; }
  }
  __syncthreads();
  if (tid < HD){
    float a = rb1[tid];
    for (int k=0;k<HD;k++) a += sH[k]*rw1[k*HD + tid];
    sRf[tid] = fmaxf(a, 0.f);
  }
  __syncthreads();
  int o = blockIdx.x*256 + tid;
  if (o < NEWP*3){
    float a = rb2[o];
    for (int k=0;k<HD;k++) a += sRf[k]*rw2[k*(NEWP*3) + o];
    canvas[((size_t)b*NMAX + N)*3 + o] = a*0.02f + centerpf[b*3 + (o%3)];
  }
}

/* ---- chamfer: dot form, SoA LDS y-tiles, flat 256-block grid ---- */
#define CYT 1024

__global__ __launch_bounds__(256) void chamfer_init_kernel(
    unsigned* __restrict__ minAB, unsigned* __restrict__ minCD)
{
  int i = blockIdx.x*256 + threadIdx.x;
  if (i < 2*BB*N0) minAB[i] = 0xFFFFFFFFu;
  if (i < BB*NNEW + BB*N0) minCD[i] = 0xFFFFFFFFu;
}

__global__ __launch_bounds__(512) void chamfer_kernel(
    const float* __restrict__ canvas, const float* __restrict__ gt,
    unsigned* __restrict__ minAB, unsigned* __restrict__ minCD)
{
  __shared__ float sy0[CYT], sy1[CYT], sy2[CYT], sny[CYT];
  int id = blockIdx.x;
  int dir, rem;
  if (id < 32){ dir=0; rem=id; }
  else if (id < 64){ dir=1; rem=id-32; }
  else if (id < 160){ dir=2; rem=id-64; }
  else { dir=3; rem=id-160; }
  int b, xb, yb;
  if (dir < 2){ b = rem>>3; int l = rem&7; xb = l>>2; yb = l&3; }
  else if (dir == 2){ b = rem/24; int l = rem%24; xb = l>>2; yb = l&3; }
  else { b = rem/24; int l = rem%24; xb = l/12; yb = l%12; }

  int Nx, Ny; const float* X; const float* Y; unsigned* mp;
  if (dir==0){      Nx=N0;   Ny=N0;   X=canvas+(size_t)b*NMAX*3;       Y=gt+(size_t)b*N0*3;            mp=minAB + b*N0; }
  else if (dir==1){ Nx=N0;   Ny=N0;   X=gt+(size_t)b*N0*3;             Y=canvas+(size_t)b*NMAX*3;      mp=minAB + BB*N0 + b*N0; }
  else if (dir==2){ Nx=NNEW; Ny=N0;   X=canvas+((size_t)b*NMAX+N0)*3;  Y=gt+(size_t)b*N0*3;            mp=minCD + b*NNEW; }
  else {            Nx=N0;   Ny=NNEW; X=gt+(size_t)b*N0*3;             Y=canvas+((size_t)b*NMAX+N0)*3; mp=minCD + BB*NNEW + b*N0; }

  int xbase = xb*2048;
  int ybase = yb*CYT;
  int tn = min(CYT, Ny - ybase);
  int tid = threadIdx.x;
  for (int t=tid; t<tn; t+=512){
    const float* yp = Y + (size_t)(ybase+t)*3;
    float y0=yp[0], y1=yp[1], y2=yp[2];
    sy0[t]=y0; sy1[t]=y1; sy2[t]=y2; sny[t]=y0*y0+y1*y1+y2*y2;
  }
  __syncthreads();

  float X0[4],X1[4],X2[4],NXr[4],MN[4]; int XI[4]; bool VA[4];
#pragma unroll
  for (int q=0;q<4;q++){
    int x = xbase + q*512 + tid;
    VA[q] = x < Nx;
    int xc = VA[q] ? x : 0;
    const float* xp = X + (size_t)xc*3;
    X0[q]=xp[0]; X1[q]=xp[1]; X2[q]=xp[2];
    NXr[q] = X0[q]*X0[q] + X1[q]*X1[q] + X2[q]*X2[q];
    MN[q] = 3.4e38f; XI[q] = xc;
  }
  const float4* v0 = (const float4*)sy0;
  const float4* v1 = (const float4*)sy1;
  const float4* v2 = (const float4*)sy2;
  const float4* vn = (const float4*)sny;
  int j4n = tn >> 2;
  for (int j=0;j<j4n;j++){
    float4 a0 = v0[j], a1 = v1[j], a2 = v2[j], an = vn[j];
#pragma unroll
    for (int e=0;e<4;e++){
      float y0 = ((const float*)&a0)[e];
      float y1 = ((const float*)&a1)[e];
      float y2 = ((const float*)&a2)[e];
      float ny = ((const float*)&an)[e];
#pragma unroll
      for (int q=0;q<4;q++){
        float dot = fmaf(X0[q], y0, fmaf(X1[q], y1, X2[q]*y2));
        float d   = fmaf(-2.f, dot, ny);
        MN[q] = fminf(MN[q], d);
      }
    }
  }
  for (int j=j4n*4; j<tn; j++){
    float y0=sy0[j], y1=sy1[j], y2=sy2[j], ny=sny[j];
#pragma unroll
    for (int q=0;q<4;q++){
      float dot = fmaf(X0[q], y0, fmaf(X1[q], y1, X2[q]*y2));
      MN[q] = fminf(MN[q], fmaf(-2.f, dot, ny));
    }
  }
#pragma unroll
  for (int q=0;q<4;q++)
    if (VA[q]) atomicMin(&mp[XI[q]], enc_f(MN[q] + NXr[q]));
}

__global__ __launch_bounds__(256) void chamfer_reduce_kernel(
    const unsigned* __restrict__ minAB, const unsigned* __restrict__ minCD,
    float* __restrict__ acc)
{
  __shared__ float red[8];
  int s = blockIdx.x, dir = s>>2, b = s&3;
  const unsigned* mp; int len;
  if (dir==0){      mp=minAB + b*N0;            len=N0; }
  else if (dir==1){ mp=minAB + BB*N0 + b*N0;    len=N0; }
  else if (dir==2){ mp=minCD + b*NNEW;          len=NNEW; }
  else {            mp=minCD + BB*NNEW + b*N0;  len=N0; }
  float v = 0.f;
  for (int i=threadIdx.x;i<len;i+=256) v += dec_f(mp[i]);
  v = block_sum(v, red);
  if (threadIdx.x==0) acc[s] = v;
}

__global__ void finish_kernel(const float* __restrict__ acc, float* __restrict__ out)
{
  if (threadIdx.x == 0 && blockIdx.x == 0){
    float cd1 = 0.f, cd2 = 0.f;
    for (int b=0;b<BB;b++) cd1 += acc[b]/(float)N0 + acc[4+b]/(float)N0;
    for (int b=0;b<BB;b++) cd2 += acc[8+b]/(float)NNEW + acc[12+b]/(float)N0;
    out[0] = 0.1f*(cd1/BB) + 1.0f*(cd2/BB);
  }
}

extern "C" void kernel_launch(void* const* d_in, const int* in_sizes, int n_in,
                              void* d_out, int out_size, void* d_ws, size_t ws_size,
                              hipStream_t stream) {
  (void)in_sizes; (void)n_in; (void)out_size; (void)ws_size;
  const float* points   = (const float*)d_in[0];
  const float* gt       = (const float*)d_in[1];
  const float* enc_w1   = (const float*)d_in[2];
  const float* enc_b1   = (const float*)d_in[3];
  const float* enc_w2   = (const float*)d_in[4];
  const float* enc_b2   = (const float*)d_in[5];
  const float* enc_w3   = (const float*)d_in[6];
  const float* enc_b3   = (const float*)d_in[7];
  const float* att_w1   = (const float*)d_in[8];
  const float* att_b1   = (const float*)d_in[9];
  const float* att_w2   = (const float*)d_in[10];
  const float* att_b2   = (const float*)d_in[11];
  const float* lstm_wih = (const float*)d_in[12];
  const float* lstm_whh = (const float*)d_in[13];
  const float* lstm_bih = (const float*)d_in[14];
  const float* lstm_bhh = (const float*)d_in[15];
  const float* ref_w1   = (const float*)d_in[16];
  const float* ref_b1   = (const float*)d_in[17];
  const float* ref_w2   = (const float*)d_in[18];
  const float* ref_b2   = (const float*)d_in[19];
  float* out = (float*)d_out;

  float* ws      = (float*)d_ws;
  float* canvas  = ws + OFF_CANVAS;
  unsigned* minAB = (unsigned*)(ws + OFF_MINAB);
  unsigned* minCD = (unsigned*)(ws + OFF_MINCD);
  unsigned* gmaxp = (unsigned*)(ws + OFF_GMAX);
  float* hb      = ws + OFF_H;     /* 2 buffers */
  float* cb      = ws + OFF_C;     /* 2 buffers */
  float* acc     = ws + OFF_ACC;
  float* centerb = ws + OFF_CENTER;
  float* w2t     = ws + OFF_W2T;
  float* partb   = ws + OFF_PART;
  float* gpartb  = ws + OFF_GPART;
  float* f2buf   = ws + OFF_F2;

  prep_kernel<<<dim3(32), 256, 0, stream>>>(enc_w2, w2t);
  init_kernel<<<dim3(192), 256, 0, stream>>>(points, canvas, hb, cb, gmaxp);

  for (int t=0; t<NSTEPS; t++){
    int off = (t==0) ? 0 : (N0 + (t-1)*NEWP);
    int M   = (t==0) ? N0 : NEWP;
    int N   = N0 + t*NEWP;
    int nbM = (M + 255)/256;
    int nbN = (N + 255)/256;
    float* h_in  = hb + (t&1)*BB*HD;
    float* h_out = hb + ((t+1)&1)*BB*HD;
    float* c_in  = cb + (t&1)*BB*HD;
    float* c_out = cb + ((t+1)&1)*BB*HD;
    enc12_kernel<<<dim3(nbM, BB, 4), 256, 0, stream>>>(canvas, enc_w1, enc_b1, w2t, enc_b2, f2buf, off, M);
    enc3_kernel<<<dim3(nbM, BB, 8), 256, 0, stream>>>(f2buf, enc_w3, enc_b3, gmaxp, M);
    lstm_main_kernel<<<dim3(32), 256, 0, stream>>>(gmaxp, h_in, lstm_wih, lstm_whh, gpartb);
    scores_kernel<<<dim3(nbN, BB), 256, 0, stream>>>(canvas, att_w1, att_b1, att_w2, att_b2, gmaxp, h_in, partb, N);
    stepA_kernel<<<dim3(BB), 1024, 0, stream>>>(canvas, partb, centerb, N, nbN);
    refine_kernel<<<dim3(14, BB), 256, 0, stream>>>(canvas, gpartb, centerb, c_in, c_out, h_out,
                                                    lstm_wih, lstm_bih, lstm_bhh,
                                                    ref_w1, ref_b1, ref_w2, ref_b2, N);
  }

  chamfer_init_kernel<<<dim3((BB*NMAX + 255)/256), 256, 0, stream>>>(minAB, minCD);
  chamfer_kernel<<<dim3(256), 512, 0, stream>>>(canvas, gt, minAB, minCD);
  chamfer_reduce_kernel<<<dim3(16), 256, 0, stream>>>(minAB, minCD, acc);
  finish_kernel<<<1, 64, 0, stream>>>(acc, out);
}